// Round 3
// baseline (213.882 us; speedup 1.0000x reference)
//
#include <hip/hip_runtime.h>
#include <hip/hip_bf16.h>

#define Bsz 2048
#define Dim 128
#define Nrows 4096

typedef float f32x4 __attribute__((ext_vector_type(4)));
typedef __bf16 bf16x8 __attribute__((ext_vector_type(8)));

// ws layout (bytes):
//   U        @ 0        : 4096*128*2  = 1 MiB   (bf16 normalized rows)
//   part     @ 1 MiB    : 4096*64*4   = 1 MiB   (per (row,strip) sum exp(S-2))
//   rs1p     @ 2 MiB    : 4096*64*4   = 1 MiB   (per (row,strip) sum lab_j*S/2)
//   rsap     @ 3 MiB    : 4096*64*4   = 1 MiB   (per (row,strip) sum S/2)
//   rowC     @ 4 MiB    : 64*4                  (per-rowblk contrib partial)
//   rowU     @ 4MiB+256 : 64*4                  (per-rowblk unsup partial)
//   counters @ 4MiB+512 : 66*4  [0..63]=cnt per rowblk, [64]=cntF, [65]=c1

// K1: normalize [z; z_aug] -> bf16 U; block 0 zeroes counters + counts labels
__global__ __launch_bounds__(256) void k_norm(const float* __restrict__ z,
                                              const float* __restrict__ za,
                                              const long long* __restrict__ labels,
                                              __bf16* __restrict__ U,
                                              int* __restrict__ counters) {
    const int wid = threadIdx.x >> 6, lane = threadIdx.x & 63;
    if (blockIdx.x == 0 && threadIdx.x < 65) counters[threadIdx.x] = 0;
    #pragma unroll
    for (int pass = 0; pass < 4; pass++) {
        const int r = blockIdx.x * 16 + pass * 4 + wid;
        const float* src = (r < Bsz) ? (z + (size_t)r * Dim) : (za + (size_t)(r - Bsz) * Dim);
        float2 x = reinterpret_cast<const float2*>(src)[lane];
        float ss = x.x * x.x + x.y * x.y;
        #pragma unroll
        for (int m = 1; m < 64; m <<= 1) ss += __shfl_xor(ss, m);
        const float sc = 1.0f / fmaxf(sqrtf(ss), 1e-12f);
        __bf16* dst = U + (size_t)r * Dim + 2 * lane;
        dst[0] = (__bf16)(x.x * sc);
        dst[1] = (__bf16)(x.y * sc);
    }
    if (blockIdx.x == 0) {
        __shared__ int ci[256];
        const int t = threadIdx.x;
        int c = 0;
        #pragma unroll
        for (int k = 0; k < 8; k++) c += (int)labels[t * 8 + k];
        ci[t] = c;
        __syncthreads();
        for (int s = 128; s > 0; s >>= 1) {
            if (t < s) ci[t] += ci[t + s];
            __syncthreads();
        }
        if (t == 0) counters[65] = ci[0];
    }
}

// K2: fused Gram/exp/raw-sums + last-block row finalize + last-block scalar combine.
// Geometry identical to the round-1 kernel that validated bit-exact:
// block = (rowblk 0..63, jchunk 0..15); wave strip = jchunk*4+wid (64 strips of 64 cols).
__global__ __launch_bounds__(256) void k_main(const __bf16* __restrict__ U,
                                              const long long* __restrict__ labels,
                                              float* __restrict__ part,
                                              float* __restrict__ rs1p,
                                              float* __restrict__ rsap,
                                              float* __restrict__ rowC,
                                              float* __restrict__ rowU,
                                              int* __restrict__ counters,
                                              float* __restrict__ out) {
    const int rowblk = blockIdx.x >> 4;
    const int jchunk = blockIdx.x & 15;
    const int wid = threadIdx.x >> 6;
    const int lane = threadIdx.x & 63;
    const int strip = jchunk * 4 + wid;
    const int rowbase = rowblk * 64;
    const int l15 = lane & 15, l4 = lane >> 4;

    // ---- A fragments (64 rows x K=128), resident in regs
    bf16x8 a[4][4];
    #pragma unroll
    for (int rf = 0; rf < 4; rf++)
        #pragma unroll
        for (int ks = 0; ks < 4; ks++)
            a[rf][ks] = *reinterpret_cast<const bf16x8*>(
                U + (size_t)(rowbase + rf * 16 + l15) * Dim + ks * 32 + l4 * 8);

    float dsum[4][4] = {{0.f}};
    float r1s[4][4] = {{0.f}};
    float ras[4][4] = {{0.f}};
    const bool diagS = (strip == rowblk);

    #pragma unroll
    for (int t = 0; t < 4; t++) {
        const int jb = strip * 64 + t * 16;
        const float labf = (labels[(jb + l15) & (Bsz - 1)] == 1) ? 1.f : 0.f;
        bf16x8 b[4];
        #pragma unroll
        for (int ks = 0; ks < 4; ks++)
            b[ks] = *reinterpret_cast<const bf16x8*>(
                U + (size_t)(jb + l15) * Dim + ks * 32 + l4 * 8);
        #pragma unroll
        for (int rf = 0; rf < 4; rf++) {
            f32x4 acc = {0.f, 0.f, 0.f, 0.f};
            #pragma unroll
            for (int ks = 0; ks < 4; ks++)
                acc = __builtin_amdgcn_mfma_f32_16x16x32_bf16(a[rf][ks], b[ks], acc, 0, 0, 0);
            const bool dg = diagS && (t == rf);
            #pragma unroll
            for (int q = 0; q < 4; q++) {
                float av = acc[q];                        // S_ij / 2
                float e = __expf(fmaf(av, 2.f, -2.f));    // exp(S_ij - 2)
                if (dg && (l15 == l4 * 4 + q)) { e = 0.f; av = 0.f; }  // j == i
                dsum[rf][q] += e;
                ras[rf][q] += av;
                r1s[rf][q] = fmaf(labf, av, r1s[rf][q]);
            }
        }
    }

    // ---- strip partials (C layout: col = lane&15, row = (lane>>4)*4 + q)
    #pragma unroll
    for (int rf = 0; rf < 4; rf++) {
        #pragma unroll
        for (int q = 0; q < 4; q++) {
            float v0 = dsum[rf][q], v1 = r1s[rf][q], v2 = ras[rf][q];
            #pragma unroll
            for (int m = 1; m < 16; m <<= 1) {
                v0 += __shfl_xor(v0, m);
                v1 += __shfl_xor(v1, m);
                v2 += __shfl_xor(v2, m);
            }
            if (l15 == 0) {
                const int row = rowbase + rf * 16 + l4 * 4 + q;
                part[(size_t)row * 64 + strip] = v0;
                rs1p[(size_t)row * 64 + strip] = v1;
                rsap[(size_t)row * 64 + strip] = v2;
            }
        }
    }

    // ---- last block of this rowblk finalizes its 64 rows
    __threadfence();       // release this block's partials (device scope)
    __syncthreads();
    __shared__ int flag;
    if (threadIdx.x == 0) flag = (atomicAdd(&counters[rowblk], 1) == 15) ? 1 : 0;
    __syncthreads();
    if (!flag) return;
    __threadfence();       // acquire all 16 blocks' partials

    const int c1 = counters[65];
    float cs = 0.f, us = 0.f;
    #pragma unroll 1
    for (int rr = 0; rr < 16; rr++) {
        const int i = rowbase + wid * 16 + rr;
        const int partner = (i < Bsz) ? i + Bsz : i - Bsz;
        float dn = part[(size_t)i * 64 + lane];
        float v1 = rs1p[(size_t)i * 64 + lane];
        float va = rsap[(size_t)i * 64 + lane];
        float u0 = (float)U[(size_t)i * Dim + 2 * lane];
        float u1 = (float)U[(size_t)i * Dim + 2 * lane + 1];
        float p0 = (float)U[(size_t)partner * Dim + 2 * lane];
        float p1 = (float)U[(size_t)partner * Dim + 2 * lane + 1];
        float dp = u0 * p0 + u1 * p1;
        #pragma unroll
        for (int m = 1; m < 64; m <<= 1) {
            dn += __shfl_xor(dn, m);
            v1 += __shfl_xor(v1, m);
            va += __shfl_xor(va, m);
            dp += __shfl_xor(dp, m);
        }
        if (lane == 0) {
            const long long lb = labels[i & (Bsz - 1)];
            const float lnD = logf(dn) + 2.0f;            // lse over j != i (row max = 2)
            const float uns = lnD - 2.0f * dp;            // pos = S(i, partner)
            const float cnt = 2.f * (float)((lb == 1) ? c1 : (Bsz - c1));
            const float sumeq = 2.f * ((lb == 1) ? v1 : (va - v1));  // diag already excluded
            const float sup = lnD - sumeq / (cnt - 1.f);
            cs += (lb == 1) ? sup : uns;
            us += uns;
        }
    }
    __shared__ float wcs[4], wus[4];
    if (lane == 0) { wcs[wid] = cs; wus[wid] = us; }
    __syncthreads();
    __shared__ int flag2;
    if (threadIdx.x == 0) {
        rowC[rowblk] = wcs[0] + wcs[1] + wcs[2] + wcs[3];
        rowU[rowblk] = wus[0] + wus[1] + wus[2] + wus[3];
        __threadfence();   // release rowC/rowU
        flag2 = (atomicAdd(&counters[64], 1) == 63) ? 1 : 0;
    }
    __syncthreads();
    if (!flag2) return;

    // ---- the 64th finalizer combines the scalar loss
    if (wid == 0) {
        __threadfence();   // acquire all rowC/rowU
        float c = rowC[lane];
        float u = rowU[lane];
        #pragma unroll
        for (int m = 1; m < 64; m <<= 1) {
            c += __shfl_xor(c, m);
            u += __shfl_xor(u, m);
        }
        if (lane == 0) out[0] = ((c1 > 0) ? c : u) / (float)Nrows;
    }
}

extern "C" void kernel_launch(void* const* d_in, const int* in_sizes, int n_in,
                              void* d_out, int out_size, void* d_ws, size_t ws_size,
                              hipStream_t stream) {
    const float* z  = (const float*)d_in[0];
    const float* za = (const float*)d_in[1];
    const long long* labels = (const long long*)d_in[2];

    char* ws = (char*)d_ws;
    __bf16* U    = (__bf16*)(ws);
    float*  part = (float*)(ws + (1u << 20));
    float*  rs1p = (float*)(ws + (2u << 20));
    float*  rsap = (float*)(ws + (3u << 20));
    float*  rowC = (float*)(ws + (4u << 20));
    float*  rowU = (float*)(ws + (4u << 20) + 256);
    int*    counters = (int*)(ws + (4u << 20) + 512);
    float*  out = (float*)d_out;

    hipLaunchKernelGGL(k_norm, dim3(256),  dim3(256), 0, stream, z, za, labels, U, counters);
    hipLaunchKernelGGL(k_main, dim3(1024), dim3(256), 0, stream, U, labels,
                       part, rs1p, rsap, rowC, rowU, counters, out);
}

// Round 4
// 63.444 us; speedup vs baseline: 3.3712x; 3.3712x over previous
//
#include <hip/hip_runtime.h>
#include <hip/hip_bf16.h>

#define Bsz 2048
#define Dim 128
#define Nrows 4096

typedef float f32x4 __attribute__((ext_vector_type(4)));
typedef __bf16 bf16x8 __attribute__((ext_vector_type(8)));

// ws layout: U @0 (1 MiB bf16), rowC @1MiB (64 f32), rowU @1MiB+256, c1 @1MiB+512

// K1: normalize [z; z_aug] -> bf16 U (16 rows/block); block 0 counts labels==1
__global__ __launch_bounds__(256) void k_norm(const float* __restrict__ z,
                                              const float* __restrict__ za,
                                              const long long* __restrict__ labels,
                                              __bf16* __restrict__ U,
                                              int* __restrict__ c1out) {
    const int wid = threadIdx.x >> 6, lane = threadIdx.x & 63;
    #pragma unroll
    for (int pass = 0; pass < 4; pass++) {
        const int r = blockIdx.x * 16 + pass * 4 + wid;
        const float* src = (r < Bsz) ? (z + (size_t)r * Dim) : (za + (size_t)(r - Bsz) * Dim);
        float2 x = reinterpret_cast<const float2*>(src)[lane];
        float ss = x.x * x.x + x.y * x.y;
        #pragma unroll
        for (int m = 1; m < 64; m <<= 1) ss += __shfl_xor(ss, m);
        const float sc = 1.0f / fmaxf(sqrtf(ss), 1e-12f);
        __bf16* dst = U + (size_t)r * Dim + 2 * lane;
        dst[0] = (__bf16)(x.x * sc);
        dst[1] = (__bf16)(x.y * sc);
    }
    if (blockIdx.x == 0) {
        __shared__ int ci[256];
        const int t = threadIdx.x;
        int c = 0;
        #pragma unroll
        for (int k = 0; k < 8; k++) c += (int)labels[t * 8 + k];
        ci[t] = c;
        __syncthreads();
        for (int s = 128; s > 0; s >>= 1) {
            if (t < s) ci[t] += ci[t + s];
            __syncthreads();
        }
        if (t == 0) c1out[0] = ci[0];
    }
}

// K2: 64 blocks x 512 threads (8 waves). Block owns 64 rows x ALL 4096 cols, so
// per-row sums complete in LDS (no fences/atomics). Wave = 64 rows x 512 cols.
// Epilogue per S-element: exp-sum, raw sum, label-masked sum; diagonal excluded
// at source; partner similarity S(i, i^2048) captured via epilogue selector.
__global__ __launch_bounds__(512) void k_gram(const __bf16* __restrict__ U,
                                              const long long* __restrict__ labels,
                                              const int* __restrict__ c1p,
                                              float* __restrict__ rowC,
                                              float* __restrict__ rowU) {
    const int rowblk = blockIdx.x;
    const int rowbase = rowblk * 64;
    const int pbase = rowbase ^ 2048;            // partner tile base (i ^ 2048)
    const int wid = threadIdx.x >> 6;            // 0..7
    const int lane = threadIdx.x & 63;
    const int l15 = lane & 15, l4 = lane >> 4;

    __shared__ float sd[64][8];   // per-(row,wave) sum exp(S-2), diag excl
    __shared__ float s1[64][8];   // per-(row,wave) sum lab_j * S/2
    __shared__ float sa[64][8];   // per-(row,wave) sum S/2
    __shared__ float dpl[64];     // S(i, partner)/2
    __shared__ float csb[8], usb[8];

    // A fragments: 64 rows x K=128, resident in regs
    bf16x8 a[4][4];
    #pragma unroll
    for (int rf = 0; rf < 4; rf++)
        #pragma unroll
        for (int ks = 0; ks < 4; ks++)
            a[rf][ks] = *reinterpret_cast<const bf16x8*>(
                U + (size_t)(rowbase + rf * 16 + l15) * Dim + ks * 32 + l4 * 8);

    float dsum[4][4] = {{0.f}};
    float r1s[4][4] = {{0.f}};
    float ras[4][4] = {{0.f}};
    const float KE1 = 2.8853900817779268f;   // 2*log2(e)
    const float KE0 = -2.8853900817779268f;

    #pragma unroll 4
    for (int t = 0; t < 32; t++) {
        const int jb = wid * 512 + t * 16;
        const float labf = (labels[(jb + l15) & (Bsz - 1)] == 1) ? 1.f : 0.f;
        bf16x8 b[4];
        #pragma unroll
        for (int ks = 0; ks < 4; ks++)
            b[ks] = *reinterpret_cast<const bf16x8*>(
                U + (size_t)(jb + l15) * Dim + ks * 32 + l4 * 8);
        #pragma unroll
        for (int rf = 0; rf < 4; rf++) {
            f32x4 acc = {0.f, 0.f, 0.f, 0.f};
            #pragma unroll
            for (int ks = 0; ks < 4; ks++)
                acc = __builtin_amdgcn_mfma_f32_16x16x32_bf16(a[rf][ks], b[ks], acc, 0, 0, 0);
            const bool dg = (jb == rowbase + rf * 16);   // tile contains diagonal
            const bool pg = (jb == pbase + rf * 16);     // tile contains partner col
            #pragma unroll
            for (int q = 0; q < 4; q++) {
                float av = acc[q];                                  // S_ij / 2
                const bool sel = (l15 == l4 * 4 + q);
                if (pg && sel) dpl[rf * 16 + l4 * 4 + q] = av;      // raw partner sim
                float e = exp2f(fmaf(av, KE1, KE0));                // exp(S_ij - 2)
                if (dg && sel) { e = 0.f; av = 0.f; }               // exclude j == i
                dsum[rf][q] += e;
                ras[rf][q] += av;
                r1s[rf][q] = fmaf(labf, av, r1s[rf][q]);
            }
        }
    }

    // per-wave strip partials: reduce 16 cols across l15 lanes
    // (C layout: col = lane&15, row = (lane>>4)*4 + q  [HW-verified])
    #pragma unroll
    for (int rf = 0; rf < 4; rf++) {
        #pragma unroll
        for (int q = 0; q < 4; q++) {
            float v0 = dsum[rf][q], v1 = r1s[rf][q], v2 = ras[rf][q];
            #pragma unroll
            for (int m = 1; m < 16; m <<= 1) {
                v0 += __shfl_xor(v0, m);
                v1 += __shfl_xor(v1, m);
                v2 += __shfl_xor(v2, m);
            }
            if (l15 == 0) {
                const int rl = rf * 16 + l4 * 4 + q;
                sd[rl][wid] = v0;
                s1[rl][wid] = v1;
                sa[rl][wid] = v2;
            }
        }
    }
    __syncthreads();

    // finalize: each wave handles 8 rows; all lanes reduce the 8 wave-strips
    const int c1 = *c1p;
    float cs = 0.f, us = 0.f;
    #pragma unroll
    for (int rr = 0; rr < 8; rr++) {
        const int rl = wid * 8 + rr;
        const int st = lane & 7;
        float dn = sd[rl][st];
        float v1 = s1[rl][st];
        float va = sa[rl][st];
        #pragma unroll
        for (int m = 1; m < 8; m <<= 1) {
            dn += __shfl_xor(dn, m);
            v1 += __shfl_xor(v1, m);
            va += __shfl_xor(va, m);
        }
        if (lane == 0) {
            const int i = rowbase + rl;
            const long long lb = labels[i & (Bsz - 1)];
            const float lnD = logf(dn) + 2.0f;            // lse over j!=i (row max = 2)
            const float uns = lnD - 2.0f * dpl[rl];       // pos = S(i, partner)
            const float cnt = 2.f * (float)((lb == 1) ? c1 : (Bsz - c1));
            const float sumeq = 2.f * ((lb == 1) ? v1 : (va - v1));
            const float sup = lnD - sumeq / (cnt - 1.f);
            cs += (lb == 1) ? sup : uns;
            us += uns;
        }
    }
    if (lane == 0) { csb[wid] = cs; usb[wid] = us; }
    __syncthreads();
    if (threadIdx.x == 0) {
        float C = 0.f, Uu = 0.f;
        #pragma unroll
        for (int w = 0; w < 8; w++) { C += csb[w]; Uu += usb[w]; }
        rowC[rowblk] = C;
        rowU[rowblk] = Uu;
    }
}

// K3: combine 64 block results -> scalar loss
__global__ __launch_bounds__(64) void k_comb(const float* __restrict__ rowC,
                                             const float* __restrict__ rowU,
                                             const int* __restrict__ c1p,
                                             float* __restrict__ out) {
    const int lane = threadIdx.x;
    float c = rowC[lane];
    float u = rowU[lane];
    #pragma unroll
    for (int m = 1; m < 64; m <<= 1) {
        c += __shfl_xor(c, m);
        u += __shfl_xor(u, m);
    }
    if (lane == 0) out[0] = ((*c1p > 0) ? c : u) / (float)Nrows;
}

extern "C" void kernel_launch(void* const* d_in, const int* in_sizes, int n_in,
                              void* d_out, int out_size, void* d_ws, size_t ws_size,
                              hipStream_t stream) {
    const float* z  = (const float*)d_in[0];
    const float* za = (const float*)d_in[1];
    const long long* labels = (const long long*)d_in[2];

    char* ws = (char*)d_ws;
    __bf16* U    = (__bf16*)(ws);
    float*  rowC = (float*)(ws + (1u << 20));
    float*  rowU = (float*)(ws + (1u << 20) + 256);
    int*    c1   = (int*)  (ws + (1u << 20) + 512);
    float*  out  = (float*)d_out;

    hipLaunchKernelGGL(k_norm, dim3(256), dim3(256), 0, stream, z, za, labels, U, c1);
    hipLaunchKernelGGL(k_gram, dim3(64),  dim3(512), 0, stream, U, labels, c1, rowC, rowU);
    hipLaunchKernelGGL(k_comb, dim3(1),   dim3(64),  0, stream, rowC, rowU, c1, out);
}

// Round 5
// 56.009 us; speedup vs baseline: 3.8187x; 1.1327x over previous
//
#include <hip/hip_runtime.h>
#include <hip/hip_bf16.h>

#define Bsz 2048
#define Dim 128
#define Nrows 4096

typedef float f32x4 __attribute__((ext_vector_type(4)));
typedef __bf16 bf16x8 __attribute__((ext_vector_type(8)));

// ws layout:
//   U    @ 0      : 4096*128*2 = 1 MiB (bf16 normalized rows)
//   part @ 1 MiB  : 4096*64*4  = 1 MiB (per (row,strip) sum exp(S-2), diag excl)
//   rs1p @ 2 MiB  : 1 MiB (per (row,strip) sum lab_j*S/2)
//   rsap @ 3 MiB  : 1 MiB (per (row,strip) sum S/2)
//   dpv  @ 4 MiB  : 4096*4 = 16 KiB (S(i,partner)/2)
//   rowC @ 4MiB+16K : 64*4 ; rowU next 256B ; c1 next

// K1: normalize [z; z_aug] -> bf16 U (16 rows/block); block 0 counts labels==1
__global__ __launch_bounds__(256) void k_norm(const float* __restrict__ z,
                                              const float* __restrict__ za,
                                              const long long* __restrict__ labels,
                                              __bf16* __restrict__ U,
                                              int* __restrict__ c1out) {
    const int wid = threadIdx.x >> 6, lane = threadIdx.x & 63;
    #pragma unroll
    for (int pass = 0; pass < 4; pass++) {
        const int r = blockIdx.x * 16 + pass * 4 + wid;
        const float* src = (r < Bsz) ? (z + (size_t)r * Dim) : (za + (size_t)(r - Bsz) * Dim);
        float2 x = reinterpret_cast<const float2*>(src)[lane];
        float ss = x.x * x.x + x.y * x.y;
        #pragma unroll
        for (int m = 1; m < 64; m <<= 1) ss += __shfl_xor(ss, m);
        const float sc = 1.0f / fmaxf(sqrtf(ss), 1e-12f);
        __bf16* dst = U + (size_t)r * Dim + 2 * lane;
        dst[0] = (__bf16)(x.x * sc);
        dst[1] = (__bf16)(x.y * sc);
    }
    if (blockIdx.x == 0) {
        __shared__ int ci[256];
        const int t = threadIdx.x;
        int c = 0;
        #pragma unroll
        for (int k = 0; k < 8; k++) c += (int)labels[t * 8 + k];
        ci[t] = c;
        __syncthreads();
        for (int s = 128; s > 0; s >>= 1) {
            if (t < s) ci[t] += ci[t + s];
            __syncthreads();
        }
        if (t == 0) c1out[0] = ci[0];
    }
}

// K2: 1024 blocks x 256 thr. block = (rowblk, jchunk); wave strip = jchunk*4+wid.
// Wave: 64 rows x 64 cols. Epilogue: exp-sum / raw-sum / label-masked-sum
// (diag excluded at source) + partner-similarity capture to dpv.
// No LDS, no syncthreads, no fences — cross-block reduce happens in K3.
__global__ __launch_bounds__(256) void k_gram(const __bf16* __restrict__ U,
                                              const long long* __restrict__ labels,
                                              float* __restrict__ part,
                                              float* __restrict__ rs1p,
                                              float* __restrict__ rsap,
                                              float* __restrict__ dpv) {
    const int rowblk = blockIdx.x >> 4;
    const int jchunk = blockIdx.x & 15;
    const int wid = threadIdx.x >> 6;
    const int lane = threadIdx.x & 63;
    const int strip = jchunk * 4 + wid;
    const int rowbase = rowblk * 64;
    const int pbase = rowbase ^ 2048;     // partner tile base
    const int l15 = lane & 15, l4 = lane >> 4;

    // A fragments: 64 rows x K=128, resident in regs
    bf16x8 a[4][4];
    #pragma unroll
    for (int rf = 0; rf < 4; rf++)
        #pragma unroll
        for (int ks = 0; ks < 4; ks++)
            a[rf][ks] = *reinterpret_cast<const bf16x8*>(
                U + (size_t)(rowbase + rf * 16 + l15) * Dim + ks * 32 + l4 * 8);

    // labels for this strip's 64 cols, hoisted (4 regs)
    float labf[4];
    #pragma unroll
    for (int t = 0; t < 4; t++)
        labf[t] = (labels[(strip * 64 + t * 16 + l15) & (Bsz - 1)] == 1) ? 1.f : 0.f;

    float dsum[4][4] = {{0.f}};
    float r1s[4][4] = {{0.f}};
    float ras[4][4] = {{0.f}};
    const float KE1 = 2.8853900817779268f;    // 2*log2(e)
    const float KE0 = -2.8853900817779268f;

    #pragma unroll
    for (int t = 0; t < 4; t++) {
        const int jb = strip * 64 + t * 16;
        bf16x8 b[4];
        #pragma unroll
        for (int ks = 0; ks < 4; ks++)
            b[ks] = *reinterpret_cast<const bf16x8*>(
                U + (size_t)(jb + l15) * Dim + ks * 32 + l4 * 8);
        #pragma unroll
        for (int rf = 0; rf < 4; rf++) {
            f32x4 acc = {0.f, 0.f, 0.f, 0.f};
            #pragma unroll
            for (int ks = 0; ks < 4; ks++)
                acc = __builtin_amdgcn_mfma_f32_16x16x32_bf16(a[rf][ks], b[ks], acc, 0, 0, 0);
            const bool dg = (jb == rowbase + rf * 16);   // tile holds diagonal
            const bool pg = (jb == pbase + rf * 16);     // tile holds partner col
            #pragma unroll
            for (int q = 0; q < 4; q++) {
                float av = acc[q];                                 // S_ij / 2
                const bool sel = (l15 == l4 * 4 + q);
                if (pg && sel) dpv[rowbase + rf * 16 + l4 * 4 + q] = av;
                float e = exp2f(fmaf(av, KE1, KE0));               // exp(S_ij - 2)
                if (dg && sel) { e = 0.f; av = 0.f; }              // exclude j == i
                dsum[rf][q] += e;
                ras[rf][q] += av;
                r1s[rf][q] = fmaf(labf[t], av, r1s[rf][q]);
            }
        }
    }

    // strip partials: reduce 16 cols across l15 lanes
    // (C layout: col = lane&15, row = (lane>>4)*4 + q  [HW-verified])
    #pragma unroll
    for (int rf = 0; rf < 4; rf++) {
        #pragma unroll
        for (int q = 0; q < 4; q++) {
            float v0 = dsum[rf][q], v1 = r1s[rf][q], v2 = ras[rf][q];
            #pragma unroll
            for (int m = 1; m < 16; m <<= 1) {
                v0 += __shfl_xor(v0, m);
                v1 += __shfl_xor(v1, m);
                v2 += __shfl_xor(v2, m);
            }
            if (l15 == 0) {
                const int row = rowbase + rf * 16 + l4 * 4 + q;
                part[row * 64 + strip] = v0;
                rs1p[row * 64 + strip] = v1;
                rsap[row * 64 + strip] = v2;
            }
        }
    }
}

// K3: 64 blocks x 256 thr. Per-row strip reduction + loss terms -> block partials.
__global__ __launch_bounds__(256) void k_row(const long long* __restrict__ labels,
                                             const int* __restrict__ c1p,
                                             const float* __restrict__ part,
                                             const float* __restrict__ rs1p,
                                             const float* __restrict__ rsap,
                                             const float* __restrict__ dpv,
                                             float* __restrict__ rowC,
                                             float* __restrict__ rowU) {
    const int wid = threadIdx.x >> 6, lane = threadIdx.x & 63;
    const int c1 = *c1p;
    float cs = 0.f, us = 0.f;
    #pragma unroll
    for (int rr = 0; rr < 16; rr++) {
        const int i = blockIdx.x * 64 + wid * 16 + rr;
        float dn = part[i * 64 + lane];
        float v1 = rs1p[i * 64 + lane];
        float va = rsap[i * 64 + lane];
        #pragma unroll
        for (int m = 1; m < 64; m <<= 1) {
            dn += __shfl_xor(dn, m);
            v1 += __shfl_xor(v1, m);
            va += __shfl_xor(va, m);
        }
        if (lane == 0) {
            const long long lb = labels[i & (Bsz - 1)];
            const float lnD = logf(dn) + 2.0f;        // lse over j != i (row max = 2)
            const float uns = lnD - 2.0f * dpv[i];    // pos = S(i, partner)
            const float cnt = 2.f * (float)((lb == 1) ? c1 : (Bsz - c1));
            const float sumeq = 2.f * ((lb == 1) ? v1 : (va - v1));
            const float sup = lnD - sumeq / (cnt - 1.f);
            cs += (lb == 1) ? sup : uns;
            us += uns;
        }
    }
    __shared__ float wcs[4], wus[4];
    if (lane == 0) { wcs[wid] = cs; wus[wid] = us; }
    __syncthreads();
    if (threadIdx.x == 0) {
        rowC[blockIdx.x] = wcs[0] + wcs[1] + wcs[2] + wcs[3];
        rowU[blockIdx.x] = wus[0] + wus[1] + wus[2] + wus[3];
    }
}

// K4: combine 64 block results -> scalar loss
__global__ __launch_bounds__(64) void k_comb(const float* __restrict__ rowC,
                                             const float* __restrict__ rowU,
                                             const int* __restrict__ c1p,
                                             float* __restrict__ out) {
    const int lane = threadIdx.x;
    float c = rowC[lane];
    float u = rowU[lane];
    #pragma unroll
    for (int m = 1; m < 64; m <<= 1) {
        c += __shfl_xor(c, m);
        u += __shfl_xor(u, m);
    }
    if (lane == 0) out[0] = ((*c1p > 0) ? c : u) / (float)Nrows;
}

extern "C" void kernel_launch(void* const* d_in, const int* in_sizes, int n_in,
                              void* d_out, int out_size, void* d_ws, size_t ws_size,
                              hipStream_t stream) {
    const float* z  = (const float*)d_in[0];
    const float* za = (const float*)d_in[1];
    const long long* labels = (const long long*)d_in[2];

    char* ws = (char*)d_ws;
    __bf16* U    = (__bf16*)(ws);
    float*  part = (float*)(ws + (1u << 20));
    float*  rs1p = (float*)(ws + (2u << 20));
    float*  rsap = (float*)(ws + (3u << 20));
    float*  dpv  = (float*)(ws + (4u << 20));
    float*  rowC = (float*)(ws + (4u << 20) + (16u << 10));
    float*  rowU = (float*)(ws + (4u << 20) + (16u << 10) + 256);
    int*    c1   = (int*)  (ws + (4u << 20) + (16u << 10) + 512);
    float*  out  = (float*)d_out;

    hipLaunchKernelGGL(k_norm, dim3(256),  dim3(256), 0, stream, z, za, labels, U, c1);
    hipLaunchKernelGGL(k_gram, dim3(1024), dim3(256), 0, stream, U, labels, part, rs1p, rsap, dpv);
    hipLaunchKernelGGL(k_row,  dim3(64),   dim3(256), 0, stream, labels, c1, part, rs1p, rsap, dpv, rowC, rowU);
    hipLaunchKernelGGL(k_comb, dim3(1),    dim3(64),  0, stream, rowC, rowU, c1, out);
}

// Round 6
// 39.175 us; speedup vs baseline: 5.4597x; 1.4297x over previous
//
#include <hip/hip_runtime.h>
#include <hip/hip_bf16.h>

#define Bsz 2048
#define Dim 128
#define Nrows 4096

typedef float f32x4 __attribute__((ext_vector_type(4)));
typedef __bf16 bf16x8 __attribute__((ext_vector_type(8)));

// ws layout:
//   U    @ 0      : 4096*128*2 = 1 MiB (bf16 normalized rows)
//   part @ 1 MiB  : 4096*64*4  = 1 MiB (per (row,strip) sum exp(S-2), diag excl)
//   rs1p @ 2 MiB  : 1 MiB (per (row,strip) sum lab_j*S/2)
//   rsap @ 3 MiB  : 1 MiB (per (row,strip) sum S/2)
//   dpv  @ 4 MiB  : 16 KiB (S(i,partner)/2)
//   rowC @ 4MiB+16K : 256*4 ; rowU @ +1K ; c1 @ +2K

// K1: normalize [z; z_aug] -> bf16 U (16 rows/block); block 0 counts labels==1
__global__ __launch_bounds__(256) void k_norm(const float* __restrict__ z,
                                              const float* __restrict__ za,
                                              const long long* __restrict__ labels,
                                              __bf16* __restrict__ U,
                                              int* __restrict__ c1out) {
    const int wid = threadIdx.x >> 6, lane = threadIdx.x & 63;
    #pragma unroll
    for (int pass = 0; pass < 4; pass++) {
        const int r = blockIdx.x * 16 + pass * 4 + wid;
        const float* src = (r < Bsz) ? (z + (size_t)r * Dim) : (za + (size_t)(r - Bsz) * Dim);
        float2 x = reinterpret_cast<const float2*>(src)[lane];
        float ss = x.x * x.x + x.y * x.y;
        #pragma unroll
        for (int m = 1; m < 64; m <<= 1) ss += __shfl_xor(ss, m);
        const float sc = 1.0f / fmaxf(sqrtf(ss), 1e-12f);
        __bf16* dst = U + (size_t)r * Dim + 2 * lane;
        dst[0] = (__bf16)(x.x * sc);
        dst[1] = (__bf16)(x.y * sc);
    }
    if (blockIdx.x == 0) {
        __shared__ int ci[256];
        const int t = threadIdx.x;
        int c = 0;
        #pragma unroll
        for (int k = 0; k < 8; k++) c += (int)labels[t * 8 + k];
        ci[t] = c;
        __syncthreads();
        for (int s = 128; s > 0; s >>= 1) {
            if (t < s) ci[t] += ci[t + s];
            __syncthreads();
        }
        if (t == 0) c1out[0] = ci[0];
    }
}

// K2: SWAPPED-OPERAND Gram: wave computes D[j][i] = mfma(A=U_j, B=U_i) so the
// row index i is lane-local (i = l15) and the j-reduction collapses in-register.
// dsum/r1s/ras are 4 regs each (per i-tile bt); cross-lane reduce = 2 shuffle
// steps across l4 (24 DS ops/wave vs 192 in the previous version).
// Labels on j come from a wave ballot bitmask. Diag excluded at source;
// partner similarity captured where j-tile == i-tile ^ 2048.
__global__ __launch_bounds__(256) void k_gram(const __bf16* __restrict__ U,
                                              const long long* __restrict__ labels,
                                              float* __restrict__ part,
                                              float* __restrict__ rs1p,
                                              float* __restrict__ rsap,
                                              float* __restrict__ dpv) {
    const int iblk = blockIdx.x >> 4;     // 0..63 : owns 64 rows i
    const int jchunk = blockIdx.x & 15;   // 0..15
    const int wid = threadIdx.x >> 6;
    const int lane = threadIdx.x & 63;
    const int strip = jchunk * 4 + wid;   // 0..63 : owns 64 cols j
    const int ibase = iblk * 64;
    const int jb0 = strip * 64;
    const int l15 = lane & 15, l4 = lane >> 4;

    // B fragments = U_i (n-side), resident: 4 i-tiles x 4 ks
    bf16x8 b[4][4];
    #pragma unroll
    for (int bt = 0; bt < 4; bt++)
        #pragma unroll
        for (int ks = 0; ks < 4; ks++)
            b[bt][ks] = *reinterpret_cast<const bf16x8*>(
                U + (size_t)(ibase + bt * 16 + l15) * Dim + ks * 32 + l4 * 8);

    // label bitmask for this strip's 64 j-cols: bit l = (labels[jb0+l] == 1)
    const long long labl = labels[(jb0 + lane) & (Bsz - 1)];
    const unsigned long long lmask = __ballot(labl == 1);

    float dsum[4] = {0.f, 0.f, 0.f, 0.f};
    float r1s[4]  = {0.f, 0.f, 0.f, 0.f};
    float ras[4]  = {0.f, 0.f, 0.f, 0.f};
    const float KE1 = 2.8853900817779268f;    // 2*log2(e)
    const float KE0 = -2.8853900817779268f;

    #pragma unroll
    for (int at = 0; at < 4; at++) {
        const int jb = jb0 + at * 16;
        bf16x8 a[4];
        #pragma unroll
        for (int ks = 0; ks < 4; ks++)
            a[ks] = *reinterpret_cast<const bf16x8*>(
                U + (size_t)(jb + l15) * Dim + ks * 32 + l4 * 8);
        // labels for this lane's 4 j values (j_local = at*16 + l4*4 + q)
        float labq[4];
        #pragma unroll
        for (int q = 0; q < 4; q++)
            labq[q] = (float)((lmask >> (at * 16 + l4 * 4 + q)) & 1ull);

        #pragma unroll
        for (int bt = 0; bt < 4; bt++) {
            f32x4 acc = {0.f, 0.f, 0.f, 0.f};
            #pragma unroll
            for (int ks = 0; ks < 4; ks++)
                acc = __builtin_amdgcn_mfma_f32_16x16x32_bf16(a[ks], b[bt][ks], acc, 0, 0, 0);
            const int itb = ibase + bt * 16;
            const bool dg = (jb == itb);            // tile holds diagonal
            const bool pg = (jb == (itb ^ 2048));   // tile holds partner col
            #pragma unroll
            for (int q = 0; q < 4; q++) {
                float av = acc[q];                  // S[j][i] / 2 == S[i][j] / 2
                const bool sel = (l15 == l4 * 4 + q);
                if (pg && sel) dpv[itb + l15] = av;
                float e = exp2f(fmaf(av, KE1, KE0));       // exp(S - 2)
                if (dg && sel) { e = 0.f; av = 0.f; }      // exclude j == i
                dsum[bt] += e;
                ras[bt] += av;
                r1s[bt] = fmaf(labq[q], av, r1s[bt]);
            }
        }
    }

    // cross-lane: sum the 4 l4-groups (j-partition); i = l15 is lane-local.
    #pragma unroll
    for (int bt = 0; bt < 4; bt++) {
        float v0 = dsum[bt], v1 = r1s[bt], v2 = ras[bt];
        v0 += __shfl_xor(v0, 16); v0 += __shfl_xor(v0, 32);
        v1 += __shfl_xor(v1, 16); v1 += __shfl_xor(v1, 32);
        v2 += __shfl_xor(v2, 16); v2 += __shfl_xor(v2, 32);
        if (l4 == 0) {
            const int row = ibase + bt * 16 + l15;
            part[row * 64 + strip] = v0;
            rs1p[row * 64 + strip] = v1;
            rsap[row * 64 + strip] = v2;
        }
    }
}

// K3: 256 blocks x 256 thr; block = 16 rows, wave = 4 rows. Strip reduce + loss.
__global__ __launch_bounds__(256) void k_row(const long long* __restrict__ labels,
                                             const int* __restrict__ c1p,
                                             const float* __restrict__ part,
                                             const float* __restrict__ rs1p,
                                             const float* __restrict__ rsap,
                                             const float* __restrict__ dpv,
                                             float* __restrict__ rowC,
                                             float* __restrict__ rowU) {
    const int wid = threadIdx.x >> 6, lane = threadIdx.x & 63;
    const int c1 = *c1p;
    float cs = 0.f, us = 0.f;
    #pragma unroll
    for (int rr = 0; rr < 4; rr++) {
        const int i = blockIdx.x * 16 + wid * 4 + rr;
        float dn = part[i * 64 + lane];
        float v1 = rs1p[i * 64 + lane];
        float va = rsap[i * 64 + lane];
        #pragma unroll
        for (int m = 1; m < 64; m <<= 1) {
            dn += __shfl_xor(dn, m);
            v1 += __shfl_xor(v1, m);
            va += __shfl_xor(va, m);
        }
        if (lane == 0) {
            const long long lb = labels[i & (Bsz - 1)];
            const float lnD = logf(dn) + 2.0f;        // lse over j != i (row max = 2)
            const float uns = lnD - 2.0f * dpv[i];    // pos = S(i, partner)
            const float cnt = 2.f * (float)((lb == 1) ? c1 : (Bsz - c1));
            const float sumeq = 2.f * ((lb == 1) ? v1 : (va - v1));
            const float sup = lnD - sumeq / (cnt - 1.f);
            cs += (lb == 1) ? sup : uns;
            us += uns;
        }
    }
    __shared__ float wcs[4], wus[4];
    if (lane == 0) { wcs[wid] = cs; wus[wid] = us; }
    __syncthreads();
    if (threadIdx.x == 0) {
        rowC[blockIdx.x] = wcs[0] + wcs[1] + wcs[2] + wcs[3];
        rowU[blockIdx.x] = wus[0] + wus[1] + wus[2] + wus[3];
    }
}

// K4: combine 256 block results -> scalar loss
__global__ __launch_bounds__(256) void k_comb(const float* __restrict__ rowC,
                                              const float* __restrict__ rowU,
                                              const int* __restrict__ c1p,
                                              float* __restrict__ out) {
    __shared__ float sc[256], su[256];
    const int t = threadIdx.x;
    sc[t] = rowC[t];
    su[t] = rowU[t];
    __syncthreads();
    for (int s = 128; s > 0; s >>= 1) {
        if (t < s) { sc[t] += sc[t + s]; su[t] += su[t + s]; }
        __syncthreads();
    }
    if (t == 0) out[0] = ((*c1p > 0) ? sc[0] : su[0]) / (float)Nrows;
}

extern "C" void kernel_launch(void* const* d_in, const int* in_sizes, int n_in,
                              void* d_out, int out_size, void* d_ws, size_t ws_size,
                              hipStream_t stream) {
    const float* z  = (const float*)d_in[0];
    const float* za = (const float*)d_in[1];
    const long long* labels = (const long long*)d_in[2];

    char* ws = (char*)d_ws;
    __bf16* U    = (__bf16*)(ws);
    float*  part = (float*)(ws + (1u << 20));
    float*  rs1p = (float*)(ws + (2u << 20));
    float*  rsap = (float*)(ws + (3u << 20));
    float*  dpv  = (float*)(ws + (4u << 20));
    float*  rowC = (float*)(ws + (4u << 20) + (16u << 10));
    float*  rowU = (float*)(ws + (4u << 20) + (17u << 10));
    int*    c1   = (int*)  (ws + (4u << 20) + (18u << 10));
    float*  out  = (float*)d_out;

    hipLaunchKernelGGL(k_norm, dim3(256),  dim3(256), 0, stream, z, za, labels, U, c1);
    hipLaunchKernelGGL(k_gram, dim3(1024), dim3(256), 0, stream, U, labels, part, rs1p, rsap, dpv);
    hipLaunchKernelGGL(k_row,  dim3(256),  dim3(256), 0, stream, labels, c1, part, rs1p, rsap, dpv, rowC, rowU);
    hipLaunchKernelGGL(k_comb, dim3(1),    dim3(256), 0, stream, rowC, rowU, c1, out);
}